// Round 2
// baseline (139.325 us; speedup 1.0000x reference)
//
#include <hip/hip_runtime.h>
#include <hip/hip_cooperative_groups.h>

#define NA 8192
#define IT 128                          // i-atoms per job (2 per lane, packed)
#define JT 64                           // j-atoms per job
#define NI (NA / IT)                    // 64 i-tile rows
#define NJOB 4160                       // sum_{I=0..63} (128 - 2I) jobs with J >= 2I
#define NBODY (NJOB * JT)               // 266240 = 4096 * 65 (exact!)
#define NWAVE 4096                      // perfectly balanced: 4 waves/SIMD on all 1024 SIMDs
#define BPW 65                          // bodies per wave (exact division)
#define WPB 8                           // waves per block
#define BLOCK (WPB * 64)                // 512 threads
#define NBLK (NWAVE / WPB)              // 512 blocks = exactly 2 per CU (co-resident!)
#define S_OF(I) ((I) * (129 - (I)))     // jobs before i-tile row I

typedef float v2f __attribute__((ext_vector_type(2)));
typedef float v4f __attribute__((ext_vector_type(4)));

namespace cg = cooperative_groups;

__global__ __launch_bounds__(BLOCK, 4) void dftd3_pair_energy(
    const float* __restrict__ pos,
    const float* __restrict__ p_a1, const float* __restrict__ p_a2,
    const float* __restrict__ p_s6, const float* __restrict__ p_s8,
    float* __restrict__ partial,
    float* __restrict__ out)
{
    const int tid  = threadIdx.x;
    const int lane = tid & 63;
    const int wv   = tid >> 6;
    const int q = __builtin_amdgcn_readfirstlane(blockIdx.x * WPB + wv);

    __shared__ v4f jtile[WPB][JT];      // per-wave broadcast buffer: no barriers ever
    __shared__ float wsum[WPB];

    const float a1 = p_a1[0], a2 = p_a2[0];
    const float s6 = p_s6[0], s8 = p_s8[0];
    const float tmp  = a1 + a2;
    const float tmp2 = tmp * tmp;
    const float tmp6 = tmp2 * tmp2 * tmp2;
    const float tmp8 = tmp6 * tmp2;
    // position pre-scale H = 2^-4 => d2 scales by 2^-8, d6 by 2^-24, d8 by 2^-32.
    // Folding 2^-24 / 2^-32 into the constants makes the old dens=den*SC mul vanish;
    // all scalings are exact powers of 2 (bit-neutral, incl. rcp(x*2^k)=rcp(x)*2^-k).
    const float H  = 0.0625f;           // 2^-4
    const float C3 = 5.9604645e-8f;     // 2^-24
    const float C4 = 2.3283064365386963e-10f; // 2^-32
    const float T6 = (tmp6 + 1e-12f) * C3;
    const float T8 = (tmp8 + 1e-12f) * C4;
    const float ns6 = -s6 * C3;         // multiplies B' (=B*2^-32) -> total 2^-56
    const float ns8 = -s8 * C4;         // multiplies A' (=A*2^-24) -> total 2^-56

    // ---- this wave's body range [65q, 65q+65): tail of jobA + head of jobA+1
    const int b0   = q * BPW;
    const int jobA = b0 >> 6;           // <= 4158, so jobA+1 <= 4159 is always valid
    const int kA   = b0 & 63;           // segA: k in [kA,64)  segB: k in [0,kA]

    // decode jobA -> (I, J); S_OF is monotone on [0,64]
    int I = (int)((129.0f - sqrtf(16641.0f - 4.0f * (float)jobA)) * 0.5f);
    if (I < 0) I = 0;
    if (I > NI - 1) I = NI - 1;
    while (S_OF(I + 1) <= jobA) ++I;
    while (S_OF(I) > jobA) --I;
    int J = 2 * I + (jobA - S_OF(I));

    v2f xim, yim, zim, peri2;
    int i0 = 0;
    int Jbase = 0;

    auto load_i = [&](int It) {
        i0 = It * IT + 2 * lane;        // lane owns atoms i0, i0+1
        v2f xr = { pos[3 * i0 + 0], pos[3 * i0 + 3] };
        v2f yr = { pos[3 * i0 + 1], pos[3 * i0 + 4] };
        v2f zr = { pos[3 * i0 + 2], pos[3 * i0 + 5] };
        v2f xs = xr * (v2f)H, ys = yr * (v2f)H, zs = zr * (v2f)H;
        peri2 = __builtin_elementwise_fma(xs, xs,
                __builtin_elementwise_fma(ys, ys, zs * zs));
        xim = xs * (v2f)-2.0f;          // -2 * scaled coords for the dot-expansion
        yim = ys * (v2f)-2.0f;
        zim = zs * (v2f)-2.0f;
    };
    auto stage_j = [&](int Jt) {        // wave-private staging, in-order LDS => no barrier
        int j = Jt * JT + lane;
        float xj = pos[3 * j + 0] * H;
        float yj = pos[3 * j + 1] * H;
        float zj = pos[3 * j + 2] * H;
        float wj = fmaf(xj, xj, fmaf(yj, yj, zj * zj));   // |pj'|^2 rides in .w
        jtile[wv][lane] = (v4f){ xj, yj, zj, wj };
    };

    v2f acc = {0.0f, 0.0f};

    // per body: 1 ds_read_b128 (uniform -> broadcast) + 12 pk-VALU + 1 mul + 1 rcp
    auto body = [&](int k, bool masked) {
        v4f pj = jtile[wv][k];          // k scalar loop var: wave-uniform LDS broadcast
        // d2' = |pi'|^2 + |pj'|^2 - 2 pi'.pj'   (4 ops instead of 6)
        v2f d2 = __builtin_elementwise_fma(xim, (v2f)pj.x,
                 __builtin_elementwise_fma(yim, (v2f)pj.y,
                 __builtin_elementwise_fma(zim, (v2f)pj.z, peri2 + pj.w)));
        v2f d4 = d2 * d2;
        v2f A  = __builtin_elementwise_fma(d4, d2, (v2f)T6);   // (d6 + T6) * 2^-24
        v2f B  = __builtin_elementwise_fma(d4, d4, (v2f)T8);   // (d8 + T8) * 2^-32
        v2f num = __builtin_elementwise_fma((v2f)ns6, B, (v2f)ns8 * A); // -(s6 B + s8 A)*2^-56
        v2f den = A * B;                // den_true * 2^-56 : in-range, no extra scaling mul
        float t = den.x * den.y;        // in [3.4e-15, 5.7e22]: safe
        float r = __builtin_amdgcn_rcpf(t);    // ONE rcp for both pairs
        if (masked) {                   // edge jobs: count only j>i (excludes self)
            int jk = Jbase + k;
            num.x = (jk > i0)     ? num.x : 0.0f;
            num.y = (jk > i0 + 1) ? num.y : 0.0f;
        }
        // rec = {1/den.x, 1/den.y} via swapped halves: v_pk_mul
        v2f rec = __builtin_shufflevector(den, den, 1, 0) * r;
        acc = __builtin_elementwise_fma(num, rec, acc);        // one v_pk_fma
    };

    auto run = [&](int k0, int k1, bool edge) {
        if (edge) {
            #pragma unroll 8
            for (int k = k0; k < k1; ++k) body(k, true);
        } else {
            #pragma unroll 8
            for (int k = k0; k < k1; ++k) body(k, false);
        }
    };

    // ---- segment A: jobA, k in [kA, 64)
    load_i(I);
    stage_j(J);
    Jbase = J * JT;
    run(kA, JT, (J - 2 * I) < 2);

    // ---- segment B: jobA+1, k in [0, kA]
    int I2 = I, J2 = J + 1;
    if (J == 127) { I2 = I + 1; J2 = 2 * I2; }   // row rollover
    if (I2 != I) load_i(I2);                      // usually reused (scalar branch)
    stage_j(J2);
    Jbase = J2 * JT;
    run(0, kA + 1, (J2 - 2 * I2) < 2);

    float accs = 2.0f * (acc.x + acc.y);   // every counted pair stands for (i,j)+(j,i)

    // ---- wave butterfly, block partial
    #pragma unroll
    for (int off = 32; off > 0; off >>= 1)
        accs += __shfl_xor(accs, off, 64);

    if (lane == 0) wsum[wv] = accs;
    __syncthreads();
    if (tid == 0) {
        float s = 0.0f;
        #pragma unroll
        for (int p = 0; p < WPB; ++p) s += wsum[p];
        atomicExch(&partial[blockIdx.x], s);   // device-coherent store of block sum
        __threadfence();
    }

    // ---- cooperative grid barrier replaces counter + memset (no init state needed:
    // poisoned d_ws is fully overwritten before any read)
    cg::this_grid().sync();

    if (blockIdx.x == 0) {
        // NBLK == BLOCK: exactly one partial per thread
        float s = atomicAdd(&partial[tid], 0.0f);  // coherent cross-XCD read
        #pragma unroll
        for (int off = 32; off > 0; off >>= 1)
            s += __shfl_xor(s, off, 64);
        if (lane == 0) wsum[wv] = s;
        __syncthreads();
        if (tid == 0) {
            float tot = 0.0f;
            #pragma unroll
            for (int p = 0; p < WPB; ++p) tot += wsum[p];
            out[0] = tot;
        }
    }
}

extern "C" void kernel_launch(void* const* d_in, const int* in_sizes, int n_in,
                              void* d_out, int out_size, void* d_ws, size_t ws_size,
                              hipStream_t stream) {
    // setup_inputs order: atomic_numbers(0), positions(1), r2r4(2), a1(3), a2(4), s6(5), s8(6)
    const float* pos = (const float*)d_in[1];
    const float* a1  = (const float*)d_in[3];
    const float* a2  = (const float*)d_in[4];
    const float* s6  = (const float*)d_in[5];
    const float* s8  = (const float*)d_in[6];
    float* partial = (float*)d_ws;                    // NBLK block sums
    float* out     = (float*)d_out;

    void* args[] = { (void*)&pos, (void*)&a1, (void*)&a2, (void*)&s6, (void*)&s8,
                     (void*)&partial, (void*)&out };
    hipLaunchCooperativeKernel(reinterpret_cast<void*>(dftd3_pair_energy),
                               dim3(NBLK), dim3(BLOCK), args, 0, stream);
}

// Round 3
// 82.286 us; speedup vs baseline: 1.6932x; 1.6932x over previous
//
#include <hip/hip_runtime.h>

#define NA 8192
#define IT 128                          // i-atoms per job (2 per lane, packed)
#define JT 64                           // j-atoms per job
#define NI (NA / IT)                    // 64 i-tile rows
#define NJOB 4160                       // sum_{I=0..63} (128 - 2I) jobs with J >= 2I
#define NBODY (NJOB * JT)               // 266240 = 4096 * 65 (exact!)
#define NWAVE 4096                      // perfectly balanced: 4 waves/SIMD on all 1024 SIMDs
#define BPW 65                          // bodies per wave (exact division)
#define WPB 8                           // waves per block
#define BLOCK (WPB * 64)                // 512 threads
#define NBLK (NWAVE / WPB)              // 512 blocks = exactly 2 per CU; NBLK == BLOCK
#define S_OF(I) ((I) * (129 - (I)))     // jobs before i-tile row I

typedef float v2f __attribute__((ext_vector_type(2)));
typedef float v4f __attribute__((ext_vector_type(4)));

// Device-global state instead of poisoned d_ws: g_cnt is 0 at module load and is
// restored to 0 by the last block each launch, so no host-side memset dispatch.
__device__ float g_partial[NBLK];
__device__ int   g_cnt = 0;

__global__ __launch_bounds__(BLOCK, 4) void dftd3_pair_energy(
    const float* __restrict__ pos,
    const float* __restrict__ p_a1, const float* __restrict__ p_a2,
    const float* __restrict__ p_s6, const float* __restrict__ p_s8,
    float* __restrict__ out)
{
    const int tid  = threadIdx.x;
    const int lane = tid & 63;
    const int wv   = tid >> 6;
    const int q = __builtin_amdgcn_readfirstlane(blockIdx.x * WPB + wv);

    __shared__ v4f jtile[WPB][JT];      // per-wave broadcast buffer: no barriers ever
    __shared__ float wsum[WPB];
    __shared__ int lastflag;

    const float a1 = p_a1[0], a2 = p_a2[0];
    const float s6 = p_s6[0], s8 = p_s8[0];
    const float tmp  = a1 + a2;
    const float tmp2 = tmp * tmp;
    const float tmp6 = tmp2 * tmp2 * tmp2;
    const float tmp8 = tmp6 * tmp2;
    // position pre-scale H = 2^-4 => d2 scales by 2^-8, d6 by 2^-24, d8 by 2^-32.
    // Folding 2^-24 / 2^-32 into the constants removes the explicit range-scale mul;
    // all scalings are exact powers of 2 (rcp(x*2^k) = rcp(x)*2^-k exactly).
    const float H  = 0.0625f;           // 2^-4
    const float C3 = 5.9604645e-8f;     // 2^-24
    const float C4 = 2.3283064365386963e-10f; // 2^-32
    const float T6 = (tmp6 + 1e-12f) * C3;
    const float T8 = (tmp8 + 1e-12f) * C4;
    const float ns6 = -s6 * C3;         // multiplies B' (=B*2^-32) -> total 2^-56
    const float ns8 = -s8 * C4;         // multiplies A' (=A*2^-24) -> total 2^-56

    // ---- this wave's body range [65q, 65q+65): tail of jobA + head of jobA+1
    const int b0   = q * BPW;
    const int jobA = b0 >> 6;           // <= 4158, so jobA+1 <= 4159 is always valid
    const int kA   = b0 & 63;           // segA: k in [kA,64)  segB: k in [0,kA]

    // decode jobA -> (I, J); S_OF is monotone on [0,64]
    int I = (int)((129.0f - sqrtf(16641.0f - 4.0f * (float)jobA)) * 0.5f);
    if (I < 0) I = 0;
    if (I > NI - 1) I = NI - 1;
    while (S_OF(I + 1) <= jobA) ++I;
    while (S_OF(I) > jobA) --I;
    int J = 2 * I + (jobA - S_OF(I));

    v2f xim, yim, zim, peri2;
    int i0 = 0;
    int Jbase = 0;

    auto load_i = [&](int It) {
        i0 = It * IT + 2 * lane;        // lane owns atoms i0, i0+1
        v2f xr = { pos[3 * i0 + 0], pos[3 * i0 + 3] };
        v2f yr = { pos[3 * i0 + 1], pos[3 * i0 + 4] };
        v2f zr = { pos[3 * i0 + 2], pos[3 * i0 + 5] };
        v2f xs = xr * (v2f)H, ys = yr * (v2f)H, zs = zr * (v2f)H;
        peri2 = __builtin_elementwise_fma(xs, xs,
                __builtin_elementwise_fma(ys, ys, zs * zs));
        xim = xs * (v2f)-2.0f;          // -2 * scaled coords for the dot-expansion
        yim = ys * (v2f)-2.0f;
        zim = zs * (v2f)-2.0f;
    };
    auto stage_j = [&](int Jt) {        // wave-private staging, in-order LDS => no barrier
        int j = Jt * JT + lane;
        float xj = pos[3 * j + 0] * H;
        float yj = pos[3 * j + 1] * H;
        float zj = pos[3 * j + 2] * H;
        float wj = fmaf(xj, xj, fmaf(yj, yj, zj * zj));   // |pj'|^2 rides in .w
        jtile[wv][lane] = (v4f){ xj, yj, zj, wj };
    };

    v2f acc = {0.0f, 0.0f};

    // per body: 1 ds_read_b128 (uniform -> broadcast) + 12 pk-VALU + 1 mul + 1 rcp
    auto body = [&](int k, bool masked) {
        v4f pj = jtile[wv][k];          // k scalar loop var: wave-uniform LDS broadcast
        // d2' = |pi'|^2 + |pj'|^2 - 2 pi'.pj'   (4 ops instead of 6)
        v2f d2 = __builtin_elementwise_fma(xim, (v2f)pj.x,
                 __builtin_elementwise_fma(yim, (v2f)pj.y,
                 __builtin_elementwise_fma(zim, (v2f)pj.z, peri2 + pj.w)));
        v2f d4 = d2 * d2;
        v2f A  = __builtin_elementwise_fma(d4, d2, (v2f)T6);   // (d6 + T6) * 2^-24
        v2f B  = __builtin_elementwise_fma(d4, d4, (v2f)T8);   // (d8 + T8) * 2^-32
        v2f num = __builtin_elementwise_fma((v2f)ns6, B, (v2f)ns8 * A); // -(s6 B + s8 A)*2^-56
        v2f den = A * B;                // den_true * 2^-56 : in-range, no extra scaling mul
        float t = den.x * den.y;        // in [3.4e-15, 5.7e22]: safe
        float r = __builtin_amdgcn_rcpf(t);    // ONE rcp for both pairs
        if (masked) {                   // edge jobs: count only j>i (excludes self)
            int jk = Jbase + k;
            num.x = (jk > i0)     ? num.x : 0.0f;
            num.y = (jk > i0 + 1) ? num.y : 0.0f;
        }
        // rec = {1/den.x, 1/den.y} via swapped halves: v_pk_mul
        v2f rec = __builtin_shufflevector(den, den, 1, 0) * r;
        acc = __builtin_elementwise_fma(num, rec, acc);        // one v_pk_fma
    };

    auto run = [&](int k0, int k1, bool edge) {
        if (edge) {
            #pragma unroll 8
            for (int k = k0; k < k1; ++k) body(k, true);
        } else {
            #pragma unroll 8
            for (int k = k0; k < k1; ++k) body(k, false);
        }
    };

    // ---- segment A: jobA, k in [kA, 64)
    load_i(I);
    stage_j(J);
    Jbase = J * JT;
    run(kA, JT, (J - 2 * I) < 2);

    // ---- segment B: jobA+1, k in [0, kA]
    int I2 = I, J2 = J + 1;
    if (J == 127) { I2 = I + 1; J2 = 2 * I2; }   // row rollover
    if (I2 != I) load_i(I2);                      // usually reused (scalar branch)
    stage_j(J2);
    Jbase = J2 * JT;
    run(0, kA + 1, (J2 - 2 * I2) < 2);

    float accs = 2.0f * (acc.x + acc.y);   // every counted pair stands for (i,j)+(j,i)

    // ---- wave butterfly, block partial
    #pragma unroll
    for (int off = 32; off > 0; off >>= 1)
        accs += __shfl_xor(accs, off, 64);

    if (lane == 0) wsum[wv] = accs;
    __syncthreads();
    if (tid == 0) {
        float s = 0.0f;
        #pragma unroll
        for (int p = 0; p < WPB; ++p) s += wsum[p];
        atomicExch(&g_partial[blockIdx.x], s); // device-coherent store of block sum
        __threadfence();                       // release: partial before counter
        int old = atomicAdd(&g_cnt, 1);
        lastflag = (old == NBLK - 1);
    }
    __syncthreads();                           // block-uniform flag
    if (lastflag) {
        __threadfence();                       // acquire
        // NBLK == BLOCK: exactly one partial per thread
        float s = atomicAdd(&g_partial[tid], 0.0f);  // coherent cross-XCD read
        #pragma unroll
        for (int off = 32; off > 0; off >>= 1)
            s += __shfl_xor(s, off, 64);
        if (lane == 0) wsum[wv] = s;
        __syncthreads();
        if (tid == 0) {
            float tot = 0.0f;
            #pragma unroll
            for (int p = 0; p < WPB; ++p) tot += wsum[p];
            out[0] = tot;
            // restore counter for the next launch (all NBLK increments have
            // already happened, so no in-flight add can follow this)
            atomicExch(&g_cnt, 0);
        }
    }
}

extern "C" void kernel_launch(void* const* d_in, const int* in_sizes, int n_in,
                              void* d_out, int out_size, void* d_ws, size_t ws_size,
                              hipStream_t stream) {
    // setup_inputs order: atomic_numbers(0), positions(1), r2r4(2), a1(3), a2(4), s6(5), s8(6)
    const float* pos = (const float*)d_in[1];
    const float* a1  = (const float*)d_in[3];
    const float* a2  = (const float*)d_in[4];
    const float* s6  = (const float*)d_in[5];
    const float* s8  = (const float*)d_in[6];
    float* out       = (float*)d_out;

    dftd3_pair_energy<<<dim3(NBLK), BLOCK, 0, stream>>>(pos, a1, a2, s6, s8, out);
}